// Round 1
// baseline (194.897 us; speedup 1.0000x reference)
//
#include <hip/hip_runtime.h>

// Haar inverse DWT: out[b,c,2y+dy,2x+dx] from 4 subbands, each (8,64,256,256) f32.
// Flatten inputs to rows of W=256 (R = 8*64*256 rows). Input row r -> output
// rows 2r (tl,tr interleaved) and 2r+1 (bl,br), where the output row-pair base
// offset is exactly r*1024 (since plane*512*512 + 2y*512 == (plane*256+y)*1024).
// Each thread consumes one float4 per subband (4 input x positions) and writes
// 4 float4 (8 top + 8 bottom floats). Pure streaming, HBM-bound.

#define W_IN 256
#define VECS_PER_ROW (W_IN / 4)   // 64

__global__ __launch_bounds__(256) void HaarIDWT_kernel(
    const float* __restrict__ ll, const float* __restrict__ lh,
    const float* __restrict__ hl, const float* __restrict__ hh,
    float* __restrict__ out, int nvec)
{
    int v = blockIdx.x * blockDim.x + threadIdx.x;
    if (v >= nvec) return;

    const int in_off = v * 4;
    float A[4], B[4], C[4], D[4];
    *reinterpret_cast<float4*>(A) = *reinterpret_cast<const float4*>(ll + in_off);
    *reinterpret_cast<float4*>(B) = *reinterpret_cast<const float4*>(lh + in_off);
    *reinterpret_cast<float4*>(C) = *reinterpret_cast<const float4*>(hl + in_off);
    *reinterpret_cast<float4*>(D) = *reinterpret_cast<const float4*>(hh + in_off);

    float top[8], bot[8];
#pragma unroll
    for (int j = 0; j < 4; ++j) {
        const float a = A[j], b = B[j], c = C[j], d = D[j];
        top[2 * j + 0] = 0.5f * (a - b - c + d);  // tl
        top[2 * j + 1] = 0.5f * (a - b + c - d);  // tr
        bot[2 * j + 0] = 0.5f * (a + b - c - d);  // bl
        bot[2 * j + 1] = 0.5f * (a + b + c + d);  // br
    }

    const int row = v >> 6;        // v / VECS_PER_ROW
    const int xv  = v & 63;        // vec index within the row
    const int otop = row * 1024 + xv * 8;   // output row 2*row, col 2*(4*xv)
    const int obot = otop + 512;            // output row 2*row+1

    *reinterpret_cast<float4*>(out + otop)     = *reinterpret_cast<float4*>(top);
    *reinterpret_cast<float4*>(out + otop + 4) = *reinterpret_cast<float4*>(top + 4);
    *reinterpret_cast<float4*>(out + obot)     = *reinterpret_cast<float4*>(bot);
    *reinterpret_cast<float4*>(out + obot + 4) = *reinterpret_cast<float4*>(bot + 4);
}

extern "C" void kernel_launch(void* const* d_in, const int* in_sizes, int n_in,
                              void* d_out, int out_size, void* d_ws, size_t ws_size,
                              hipStream_t stream) {
    const float* ll = (const float*)d_in[0];
    const float* lh = (const float*)d_in[1];
    const float* hl = (const float*)d_in[2];
    const float* hh = (const float*)d_in[3];
    float* out = (float*)d_out;

    const int n    = in_sizes[0];        // 8*64*256*256 = 33,554,432
    const int nvec = n / 4;              // 8,388,608 float4's per subband

    const int block = 256;
    const int grid  = (nvec + block - 1) / block;   // 32768
    HaarIDWT_kernel<<<grid, block, 0, stream>>>(ll, lh, hl, hh, out, nvec);
}